// Round 7
// baseline (228.085 us; speedup 1.0000x reference)
//
#include <hip/hip_runtime.h>

#define NMET 200000
#define NRXN 400000
#define ESUB 800000
#define EALL 1600000
#define NBLK ((NRXN + 255) / 256)   // 1563 scan blocks (rxn CSR)

// met-bucket sort: bucket = met >> 9  (512 mets / bucket)
#define BSHIFT 9
#define NBUCK 391                    // ceil(200000 / 512)
#define EB  8192                     // met_all edges per front/scatter block
#define EB2 4096                     // met_sub edges per front/scatter block
#define NB  196                      // ceil(EALL/EB) == ceil(ESUB/EB2)

// c_target = 1 + 0.5*sin(2*pi*100/1000) = 1.2938926261462366
#define C_TARGET 1.29389262614623664f
#define DT_C 0.01f
#define HOMEO_C 0.1f
#define LOG2_10 3.32192809488736235f

__device__ __forceinline__ float fast_tanh(float x) {
    float e = __expf(2.0f * x);
    return 1.0f - 2.0f * __builtin_amdgcn_rcpf(e + 1.0f);
}

// ---- 1. fused front: rxn histogram atomics (wall) + both met-bucket counts -
__global__ __launch_bounds__(256) void k_front(
    const int* __restrict__ met_all, const int* __restrict__ met_sub,
    const int* __restrict__ rxn_sub,
    int* __restrict__ cnt, int* __restrict__ rank,
    int* __restrict__ blockHistA, int* __restrict__ blockHistS)
{
    __shared__ int hA[NBUCK];
    __shared__ int hS[NBUCK];
    int t = threadIdx.x;
    for (int b = t; b < NBUCK; b += 256) { hA[b] = 0; hS[b] = 0; }
    __syncthreads();

    int baseA = blockIdx.x * EB;
    for (int i = t; i < EB; i += 256) {
        int e = baseA + i;
        if (e < EALL) atomicAdd(&hA[met_all[e] >> BSHIFT], 1);
    }
    int baseS = blockIdx.x * EB2;
    for (int i = t; i < EB2; i += 256) {
        int e = baseS + i;
        if (e < ESUB) {
            rank[e] = atomicAdd(&cnt[rxn_sub[e]], 1);   // the device-atomic wall
            atomicAdd(&hS[met_sub[e] >> BSHIFT], 1);    // hides under it
        }
    }
    __syncthreads();
    for (int b = t; b < NBUCK; b += 256) {
        blockHistA[(size_t)b * NB + blockIdx.x] = hA[b];   // bucket-major
        blockHistS[(size_t)b * NB + blockIdx.x] = hS[b];
    }
}

// ---- 2. per-256-block sums of cnt (rxn CSR) --------------------------------
__global__ __launch_bounds__(256) void k_bsum(
    const int* __restrict__ cnt, int* __restrict__ bsum)
{
    __shared__ int lds[256];
    int i = blockIdx.x * 256 + threadIdx.x;
    lds[threadIdx.x] = (i < NRXN) ? cnt[i] : 0;
    __syncthreads();
    for (int off = 128; off > 0; off >>= 1) {
        if (threadIdx.x < off) lds[threadIdx.x] += lds[threadIdx.x + off];
        __syncthreads();
    }
    if (threadIdx.x == 0) bsum[blockIdx.x] = lds[0];
}

// ---- 3. single-block exclusive scan of the block sums ----------------------
__global__ __launch_bounds__(256) void k_scan_top(
    const int* __restrict__ bsum, int* __restrict__ boff, int nb)
{
    __shared__ int lds[256];
    __shared__ int carry_s;
    if (threadIdx.x == 0) carry_s = 0;
    __syncthreads();
    for (int base = 0; base < nb; base += 256) {
        int i = base + threadIdx.x;
        int val = (i < nb) ? bsum[i] : 0;
        lds[threadIdx.x] = val;
        __syncthreads();
        for (int off = 1; off < 256; off <<= 1) {
            int add = (threadIdx.x >= off) ? lds[threadIdx.x - off] : 0;
            __syncthreads();
            lds[threadIdx.x] += add;
            __syncthreads();
        }
        int incl = lds[threadIdx.x];
        int carry = carry_s;
        if (i < nb) boff[i] = carry + incl - val;
        __syncthreads();
        if (threadIdx.x == 255) carry_s = carry + incl;
        __syncthreads();
    }
}

// ---- 4. per-reaction global offsets (block scan + boff) --------------------
__global__ __launch_bounds__(256) void k_offsets(
    const int* __restrict__ cnt, const int* __restrict__ boff,
    int* __restrict__ offset)
{
    __shared__ int lds[256];
    int i = blockIdx.x * 256 + threadIdx.x;
    int val = (i < NRXN) ? cnt[i] : 0;
    lds[threadIdx.x] = val;
    __syncthreads();
    for (int off = 1; off < 256; off <<= 1) {
        int add = (threadIdx.x >= off) ? lds[threadIdx.x - off] : 0;
        __syncthreads();
        lds[threadIdx.x] += add;
        __syncthreads();
    }
    if (i < NRXN) offset[i] = boff[blockIdx.x] + lds[threadIdx.x] - val;
}

// ---- 5. scatter edge ids into CSR slots (plain stores) ---------------------
__global__ __launch_bounds__(256) void k_scatter(
    const int* __restrict__ rxn_sub, const int* __restrict__ offset,
    const int* __restrict__ rank, int* __restrict__ slot_edge)
{
    int e = blockIdx.x * 256 + threadIdx.x;
    if (e >= ESUB) return;
    slot_edge[offset[rxn_sub[e]] + rank[e]] = e;
}

// ---- 6. per-bucket scan over NB block counts (in place -> exclusive) -------
__global__ __launch_bounds__(256) void k_bscan(
    int* __restrict__ blockHist, int* __restrict__ btotal)
{
    __shared__ int lds[256];
    int b = blockIdx.x;
    int t = threadIdx.x;
    int val = (t < NB) ? blockHist[(size_t)b * NB + t] : 0;
    lds[t] = val;
    __syncthreads();
    for (int off = 1; off < 256; off <<= 1) {
        int add = (t >= off) ? lds[t - off] : 0;
        __syncthreads();
        lds[t] += add;
        __syncthreads();
    }
    if (t < NB) blockHist[(size_t)b * NB + t] = lds[t] - val;
    if (t == NB - 1) btotal[b] = lds[t];
}

// ---- 7. one-block scan of bucket totals -> bucketStart ---------------------
__global__ __launch_bounds__(512) void k_bstart(
    const int* __restrict__ btotal, int* __restrict__ bucketStart)
{
    __shared__ int lds[512];
    int t = threadIdx.x;
    int val = (t < NBUCK) ? btotal[t] : 0;
    lds[t] = val;
    __syncthreads();
    for (int off = 1; off < 512; off <<= 1) {
        int add = (t >= off) ? lds[t - off] : 0;
        __syncthreads();
        lds[t] += add;
        __syncthreads();
    }
    if (t < NBUCK) bucketStart[t] = lds[t] - val;
    if (t == 511) bucketStart[NBUCK] = lds[511];
}

// ---- 8. slot-parallel edge MLP; everything written coalesced at slot i -----
__global__ __launch_bounds__(256) void k_msg(
    const float* __restrict__ x, const int* __restrict__ met_sub,
    const float* __restrict__ sto_sub, const int* __restrict__ slot_edge,
    const float* __restrict__ sub_w1, const float* __restrict__ sub_b1,
    const float* __restrict__ sub_w2,
    float4* __restrict__ msgA, float4* __restrict__ msgB,
    float* __restrict__ extS, int* __restrict__ metS)
{
    __shared__ float sW1[128];
    __shared__ float sB1[64];
    __shared__ __align__(16) float sW2[512];
    int t = threadIdx.x;
    for (int i = t; i < 128; i += 256) sW1[i] = sub_w1[i];
    for (int i = t; i < 64;  i += 256) sB1[i] = sub_b1[i];
    for (int i = t; i < 512; i += 256) sW2[i] = sub_w2[i];
    __syncthreads();

    int i = blockIdx.x * 256 + t;
    if (i >= ESUB) return;
    int e = slot_edge[i];                 // contiguous read
    int m = met_sub[e];                   // random 4B, L2-resident (3.2 MB)
    float st = sto_sub[e];                // random 4B, L2-resident
    float c  = x[(size_t)m * 8 + 3];      // random, L2/L3-resident (6.4 MB)
    float ex = x[(size_t)m * 8 + 4];

    float m0 = 0.f, m1 = 0.f, m2 = 0.f, m3 = 0.f;
    float m4 = 0.f, m5 = 0.f, m6 = 0.f, m7 = 0.f;
    #pragma unroll 8
    for (int j = 0; j < 64; ++j) {
        float z = fmaf(c, sW1[j], fmaf(st, sW1[64 + j], sB1[j]));
        float th = fast_tanh(z);
        float4 wa = *(const float4*)&sW2[j * 8];
        float4 wb = *(const float4*)&sW2[j * 8 + 4];
        m0 = fmaf(th, wa.x, m0); m1 = fmaf(th, wa.y, m1);
        m2 = fmaf(th, wa.z, m2); m3 = fmaf(th, wa.w, m3);
        m4 = fmaf(th, wb.x, m4); m5 = fmaf(th, wb.y, m5);
        m6 = fmaf(th, wb.z, m6); m7 = fmaf(th, wb.w, m7);
    }
    msgA[i] = make_float4(m0, m1, m2, m3);
    msgB[i] = make_float4(m4, m5, m6, m7);
    extS[i] = ex;
    metS[i] = m;
}

// ---- 9. per-reaction: contiguous msg segment sum, rate MLP -> v ------------
__global__ __launch_bounds__(256) void k_rxn3(
    const int* __restrict__ cnt, const int* __restrict__ offset,
    const float4* __restrict__ msgA, const float4* __restrict__ msgB,
    const float* __restrict__ extS,
    const float* __restrict__ sub_b2,
    const float* __restrict__ rate_w1, const float* __restrict__ rate_b1,
    const float* __restrict__ rate_w2, const float* __restrict__ rate_b2,
    const float* __restrict__ log_k, float* __restrict__ v)
{
    __shared__ __align__(16) float sR1[512];
    __shared__ float sRB1[64];
    __shared__ float sR2[64];
    __shared__ float sB2[8];
    __shared__ float sRB2;
    int t = threadIdx.x;
    for (int i = t; i < 512; i += 256) sR1[i] = rate_w1[i];
    if (t < 64) { sRB1[t] = rate_b1[t]; sR2[t] = rate_w2[t]; }
    if (t < 8) sB2[t] = sub_b2[t];
    if (t == 64) sRB2 = rate_b2[0];
    __syncthreads();

    int r = blockIdx.x * 256 + t;
    if (r >= NRXN) return;
    int n = cnt[r];
    int base = offset[r];
    float fn = (float)n;

    float h0 = fn * sB2[0], h1 = fn * sB2[1], h2 = fn * sB2[2], h3 = fn * sB2[3];
    float h4 = fn * sB2[4], h5 = fn * sB2[5], h6 = fn * sB2[6], h7 = fn * sB2[7];
    float exs = 0.f;
    for (int i = 0; i < n; ++i) {
        float4 a = msgA[base + i];
        float4 b = msgB[base + i];
        h0 += a.x; h1 += a.y; h2 += a.z; h3 += a.w;
        h4 += b.x; h5 += b.y; h6 += b.z; h7 += b.w;
        exs += extS[base + i];
    }

    float acc = sRB2;
    #pragma unroll 4
    for (int j = 0; j < 64; ++j) {
        float z = sRB1[j];
        z = fmaf(h0, sR1[j],       z);
        z = fmaf(h1, sR1[64 + j],  z);
        z = fmaf(h2, sR1[128 + j], z);
        z = fmaf(h3, sR1[192 + j], z);
        z = fmaf(h4, sR1[256 + j], z);
        z = fmaf(h5, sR1[320 + j], z);
        z = fmaf(h6, sR1[384 + j], z);
        z = fmaf(h7, sR1[448 + j], z);
        acc = fmaf(fast_tanh(z), sR2[j], acc);
    }
    float nmax = fmaxf(fn, 1.0f);
    float ext_mean = 2.0f * exs * __builtin_amdgcn_rcpf(nmax);
    float kk = exp2f(log_k[r] * LOG2_10);
    v[r] = kk * ext_mean * acc;
}

// ---- 10. consume bucket-scatter (edge order, pre-limit v) ------------------
__global__ __launch_bounds__(256) void k_cons_scatter(
    const int* __restrict__ met_sub, const int* __restrict__ rxn_sub,
    const float* __restrict__ sto_sub, const float* __restrict__ v,
    const int* __restrict__ blockHistS, const int* __restrict__ bucketStartS,
    uint2* __restrict__ recsS)
{
    __shared__ int h[NBUCK];
    __shared__ int bbase[NBUCK];
    int t = threadIdx.x;
    for (int b = t; b < NBUCK; b += 256) {
        h[b] = 0;
        bbase[b] = bucketStartS[b] + blockHistS[(size_t)b * NB + blockIdx.x];
    }
    __syncthreads();
    int base = blockIdx.x * EB2;
    for (int i = t; i < EB2; i += 256) {
        int e = base + i;
        if (e < ESUB) {
            int m = met_sub[e];
            int b = m >> BSHIFT;
            float val = sto_sub[e] * v[rxn_sub[e]] * DT_C;
            int r = atomicAdd(&h[b], 1);
            uint2 rec;
            rec.x = (unsigned)m;
            rec.y = __float_as_uint(val);
            recsS[bbase[b] + r] = rec;
        }
    }
}

// ---- 11. per-bucket accumulate total -> met_scale (fused) ------------------
__global__ __launch_bounds__(256) void k_baccum_tot(
    const uint2* __restrict__ recsS, const int* __restrict__ bucketStartS,
    const float* __restrict__ x, float* __restrict__ met_scale)
{
    __shared__ float acc[512];
    int b = blockIdx.x;
    int t = threadIdx.x;
    for (int j = t; j < 512; j += 256) acc[j] = 0.f;
    __syncthreads();
    int s = bucketStartS[b], epos = bucketStartS[b + 1];
    for (int i = s + t; i < epos; i += 256) {
        uint2 rec = recsS[i];
        atomicAdd(&acc[rec.x & 511], __uint_as_float(rec.y));
    }
    __syncthreads();
    int mbase = b << BSHIFT;
    for (int j = t; j < 512; j += 256) {
        int m = mbase + j;
        if (m < NMET) {
            float tot = acc[j];
            float ms = 1.0f;
            if (tot > 1e-12f) ms = fminf(x[(size_t)m * 8 + 3] / tot, 1.0f);
            met_scale[m] = ms;
        }
    }
}

// ---- 12. per-reaction min over contiguous metS + v scale -------------------
__global__ __launch_bounds__(256) void k_rscale(
    const int* __restrict__ cnt, const int* __restrict__ offset,
    const int* __restrict__ metS, const float* __restrict__ met_scale,
    float* __restrict__ v)
{
    int r = blockIdx.x * 256 + threadIdx.x;
    if (r >= NRXN) return;
    int n = cnt[r];
    int base = offset[r];
    float ms = 1.0f;
    for (int i = 0; i < n; ++i)
        ms = fminf(ms, met_scale[metS[base + i]]);
    v[r] *= ms;
}

// ---- 13. contrib bucket-scatter (edge order, post-limit v) -----------------
__global__ __launch_bounds__(256) void k_bscatter(
    const int* __restrict__ met_all, const int* __restrict__ rxn_all,
    const float* __restrict__ sto_all, const float* __restrict__ v,
    const int* __restrict__ blockHistA, const int* __restrict__ bucketStartA,
    uint2* __restrict__ recsA)
{
    __shared__ int h[NBUCK];
    __shared__ int bbase[NBUCK];
    int t = threadIdx.x;
    for (int b = t; b < NBUCK; b += 256) {
        h[b] = 0;
        bbase[b] = bucketStartA[b] + blockHistA[(size_t)b * NB + blockIdx.x];
    }
    __syncthreads();
    int base = blockIdx.x * EB;
    for (int i = t; i < EB; i += 256) {
        int e = base + i;
        if (e < EALL) {
            int m = met_all[e];
            int b = m >> BSHIFT;
            float val = sto_all[e] * v[rxn_all[e]];
            int r = atomicAdd(&h[b], 1);
            uint2 rec;
            rec.x = (unsigned)m;
            rec.y = __float_as_uint(val);
            recsA[bbase[b] + r] = rec;
        }
    }
}

// ---- 14. per-bucket accumulate + homeostasis epilogue ----------------------
__global__ __launch_bounds__(256) void k_baccum(
    const uint2* __restrict__ recsA, const int* __restrict__ bucketStartA,
    const float* __restrict__ x, float* __restrict__ out)
{
    __shared__ float acc[512];
    int b = blockIdx.x;
    int t = threadIdx.x;
    for (int j = t; j < 512; j += 256) acc[j] = 0.f;
    __syncthreads();
    int s = bucketStartA[b], epos = bucketStartA[b + 1];
    for (int i = s + t; i < epos; i += 256) {
        uint2 rec = recsA[i];
        atomicAdd(&acc[rec.x & 511], __uint_as_float(rec.y));
    }
    __syncthreads();
    int mbase = b << BSHIFT;
    for (int j = t; j < 512; j += 256) {
        int m = mbase + j;
        if (m < NMET) {
            float c = x[(size_t)m * 8 + 3];
            out[m] = acc[j] - HOMEO_C * (c - C_TARGET);
        }
    }
}

extern "C" void kernel_launch(void* const* d_in, const int* in_sizes, int n_in,
                              void* d_out, int out_size, void* d_ws, size_t ws_size,
                              hipStream_t stream) {
    const float* x       = (const float*)d_in[0];
    const int*   met_sub = (const int*)  d_in[1];
    const int*   rxn_sub = (const int*)  d_in[2];
    const float* sto_sub = (const float*)d_in[3];
    const int*   met_all = (const int*)  d_in[4];
    const int*   rxn_all = (const int*)  d_in[5];
    const float* sto_all = (const float*)d_in[6];
    const float* sub_w1  = (const float*)d_in[7];
    const float* sub_b1  = (const float*)d_in[8];
    const float* sub_w2  = (const float*)d_in[9];
    const float* sub_b2  = (const float*)d_in[10];
    const float* rate_w1 = (const float*)d_in[11];
    const float* rate_b1 = (const float*)d_in[12];
    const float* rate_w2 = (const float*)d_in[13];
    const float* rate_b2 = (const float*)d_in[14];
    const float* log_k   = (const float*)d_in[15];

    char* ws = (char*)d_ws;
    // 16B-aligned big arrays first
    float4* msgA = (float4*)ws;                               // ESUB
    float4* msgB = msgA + ESUB;                               // ESUB
    uint2*  recsS = (uint2*)(msgB + ESUB);                    // ESUB
    uint2*  recsA = recsS + ESUB;                             // EALL
    float*  extS  = (float*)(recsA + EALL);                   // ESUB
    int*    metS  = (int*)(extS + ESUB);                      // ESUB
    float*  v     = (float*)(metS + ESUB);                    // NRXN
    float*  met_scale = v + NRXN;                             // NMET
    int*    rank  = (int*)(met_scale + NMET);                 // ESUB
    int*    offset = rank + ESUB;                             // NRXN
    int*    bsum  = offset + NRXN;                            // 2048
    int*    boff  = bsum + 2048;                              // 2048
    int*    slot_edge = boff + 2048;                          // ESUB
    int*    blockHistA = slot_edge + ESUB;                    // NBUCK*NB
    int*    blockHistS = blockHistA + (size_t)NBUCK * NB;     // NBUCK*NB
    int*    btotalA = blockHistS + (size_t)NBUCK * NB;        // NBUCK
    int*    bucketStartA = btotalA + NBUCK;                   // NBUCK+1
    int*    btotalS = bucketStartA + (NBUCK + 1);             // NBUCK
    int*    bucketStartS = btotalS + NBUCK;                   // NBUCK+1
    int*    cnt = bucketStartS + (NBUCK + 1);                 // NRXN [zeroed]
    float*  out = (float*)d_out;

    hipMemsetAsync(cnt, 0, (size_t)NRXN * sizeof(int), stream);

    dim3 blk(256);
    k_front<<<dim3(NB), blk, 0, stream>>>(
        met_all, met_sub, rxn_sub, cnt, rank, blockHistA, blockHistS);
    k_bsum<<<dim3(NBLK), blk, 0, stream>>>(cnt, bsum);
    k_scan_top<<<dim3(1), blk, 0, stream>>>(bsum, boff, NBLK);
    k_offsets<<<dim3(NBLK), blk, 0, stream>>>(cnt, boff, offset);
    k_bscan<<<dim3(NBUCK), blk, 0, stream>>>(blockHistA, btotalA);
    k_bstart<<<dim3(1), dim3(512), 0, stream>>>(btotalA, bucketStartA);
    k_bscan<<<dim3(NBUCK), blk, 0, stream>>>(blockHistS, btotalS);
    k_bstart<<<dim3(1), dim3(512), 0, stream>>>(btotalS, bucketStartS);
    k_scatter<<<dim3((ESUB + 255) / 256), blk, 0, stream>>>(
        rxn_sub, offset, rank, slot_edge);
    k_msg<<<dim3((ESUB + 255) / 256), blk, 0, stream>>>(
        x, met_sub, sto_sub, slot_edge, sub_w1, sub_b1, sub_w2,
        msgA, msgB, extS, metS);
    k_rxn3<<<dim3((NRXN + 255) / 256), blk, 0, stream>>>(
        cnt, offset, msgA, msgB, extS, sub_b2,
        rate_w1, rate_b1, rate_w2, rate_b2, log_k, v);
    k_cons_scatter<<<dim3(NB), blk, 0, stream>>>(
        met_sub, rxn_sub, sto_sub, v, blockHistS, bucketStartS, recsS);
    k_baccum_tot<<<dim3(NBUCK), blk, 0, stream>>>(
        recsS, bucketStartS, x, met_scale);
    k_rscale<<<dim3((NRXN + 255) / 256), blk, 0, stream>>>(
        cnt, offset, metS, met_scale, v);
    k_bscatter<<<dim3(NB), blk, 0, stream>>>(
        met_all, rxn_all, sto_all, v, blockHistA, bucketStartA, recsA);
    k_baccum<<<dim3(NBUCK), blk, 0, stream>>>(recsA, bucketStartA, x, out);
}